// Round 7
// baseline (1094.648 us; speedup 1.0000x reference)
//
#include <hip/hip_runtime.h>
#include <hip/hip_bf16.h>
#include <math.h>

#define TOK 8192   // B*L
#define DM 512
#define NH 8
#define DKH 64
#define DFFN 2048
#define SEQ 1024
#define NBLK 4
#define NUMC 1000

typedef __attribute__((ext_vector_type(8))) short bf16x8;
typedef __attribute__((ext_vector_type(4))) float f32x4;
typedef __attribute__((ext_vector_type(4))) ushort u16x4;
typedef __hip_bfloat16 bf16;

__device__ __forceinline__ void gload_lds16(const ushort* g, ushort* l) {
    __builtin_amdgcn_global_load_lds(
        (const __attribute__((address_space(1))) void*)g,
        (__attribute__((address_space(3))) void*)l, 16, 0, 0);
}

// raw workgroup barrier WITHOUT the compiler's vmcnt(0)/lgkmcnt(0) drain;
// empty asm = compiler-level memory fence so LDS ops can't migrate across.
__device__ __forceinline__ void wgbar() {
    asm volatile("" ::: "memory");
    __builtin_amdgcn_s_barrier();
    asm volatile("" ::: "memory");
}

__device__ __forceinline__ float bf2f(short u) {
    return __uint_as_float((unsigned)(unsigned short)u << 16);
}

// ---------------------------------------------------------------- embed (wave-per-token, vectorized)
__global__ __launch_bounds__(256) void embed_kernel(
    const int* __restrict__ q, const int* __restrict__ r,
    const float* __restrict__ ctx_emb, const float* __restrict__ val_emb,
    const float* __restrict__ pos_emb,
    float* __restrict__ ctx32, float* __restrict__ val32,
    bf16* __restrict__ ctx16, bf16* __restrict__ val16)
{
    const int wave = threadIdx.x >> 6, lane = threadIdx.x & 63;
    const int t = blockIdx.x * 4 + wave;
    const int inter = q[t] + NUMC * r[t];
    const int l = t & (SEQ - 1);
    const int d0 = lane * 8;
    const float* ce = ctx_emb + (size_t)inter * DM + d0;
    const float* ve = val_emb + (size_t)inter * DM + d0;
    const float* pe = pos_emb + (size_t)l * DM + d0;
    const size_t o = (size_t)t * DM + d0;
    float c[8], v[8];
#pragma unroll
    for (int j = 0; j < 8; j += 4) {
        const float4 pv = *(const float4*)&pe[j];
        const float4 cv = *(const float4*)&ce[j];
        const float4 vv = *(const float4*)&ve[j];
        c[j] = cv.x + pv.x; c[j+1] = cv.y + pv.y; c[j+2] = cv.z + pv.z; c[j+3] = cv.w + pv.w;
        v[j] = vv.x + pv.x; v[j+1] = vv.y + pv.y; v[j+2] = vv.z + pv.z; v[j+3] = vv.w + pv.w;
        *(float4*)&ctx32[o + j] = (float4){c[j], c[j+1], c[j+2], c[j+3]};
        *(float4*)&val32[o + j] = (float4){v[j], v[j+1], v[j+2], v[j+3]};
    }
    union { bf16x8 vv; ushort u[8]; } pc, pv2;
#pragma unroll
    for (int j = 0; j < 8; ++j) {
        bf16 tc = __float2bfloat16(c[j]); pc.u[j] = *(ushort*)&tc;
        bf16 tv = __float2bfloat16(v[j]); pv2.u[j] = *(ushort*)&tv;
    }
    *(bf16x8*)&ctx16[o] = pc.vv;
    *(bf16x8*)&val16[o] = pv2.vv;
}

// ---------------------------------------------------------------- transpose+cvt (weight pairs via z)
__global__ __launch_bounds__(256) void transpose_pair_kernel(
    const float* __restrict__ srcA, const float* __restrict__ srcB,
    bf16* __restrict__ dstA, bf16* __restrict__ dstB,
    int K, int N, long sb, long db, int zsplit)
{
    __shared__ float t[32][33];
    const int z = blockIdx.z;
    const float* src; bf16* dst;
    if (z < zsplit) { src = srcA + (long)z * sb;            dst = dstA + (long)z * db; }
    else            { src = srcB + (long)(z - zsplit) * sb; dst = dstB + (long)(z - zsplit) * db; }
    const int n0 = blockIdx.x * 32;
    const int k0 = blockIdx.y * 32;
    const int tx = threadIdx.x;
    const int ty = threadIdx.y;
    for (int i = ty; i < 32; i += 8) t[i][tx] = src[(size_t)(k0 + i) * N + n0 + tx];
    __syncthreads();
    for (int i = ty; i < 32; i += 8)
        dst[(size_t)(n0 + i) * K + k0 + tx] = __float2bfloat16(t[tx][i]);
}

// ---------------------------------------------------------------- MFMA GEMM (128-tile, R5 structure)
// blockIdx.z==1 selects the second problem (A1/Bt1/bias1_1/Cv1) with its own
// N (Nz) and vtmode (vtz), split forced to 1<<30; blocks whose bn >= N exit.
template<int BN, bool OUTBF16>
__global__ __launch_bounds__(256, 3) void mfma_gemm(
    const ushort* __restrict__ A, const ushort* __restrict__ Bt,
    const float* __restrict__ bias1, const float* __restrict__ bias2, int split,
    void* __restrict__ Cv, int N, int K, int relu, int vtmode,
    const ushort* __restrict__ A1, const ushort* __restrict__ Bt1,
    const float* __restrict__ bias1_1, void* __restrict__ Cv1,
    int Nz, int vtz)
{
    if (blockIdx.z) { A = A1; Bt = Bt1; bias1 = bias1_1; Cv = Cv1; N = Nz; vtmode = vtz; split = 1 << 30; }
    constexpr int MI = (BN == 128) ? 4 : 2;
    constexpr int BR = BN / 32;
    __shared__ ushort As[128 * 64];
    __shared__ ushort Bs[BN * 64];
    const int tid = threadIdx.x;
    const int wave = tid >> 6;
    const int lane = tid & 63;
    const int ln = lane & 15;
    const int kq = lane >> 4;
    const int nx = gridDim.x;
    const int lin = blockIdx.x + nx * blockIdx.y;
    const int loc = lin >> 3;
    const int mdiv = loc / nx;
    const int bm = ((lin & 7) + 8 * mdiv) * 128;
    const int bn = (loc - mdiv * nx) * BN;
    if (bn >= N) return;   // idle column (merged-dispatch padding); block-uniform
    const int wr = (BN == 128) ? (wave >> 1) * 64 : wave * 32;
    const int wc = (BN == 128) ? (wave & 1) * 64 : 0;

    const int trow = tid >> 3;
    const int gcb = (tid & 7) ^ (trow & 7);
    const ushort* Ab = A + (size_t)(bm + trow) * K + gcb * 8;
    const ushort* Bb = Bt + (size_t)(bn + trow) * K + gcb * 8;
    ushort* AsW = As + wave * 512;
    ushort* BsW = Bs + wave * 512;

    f32x4 acc[MI][4];
#pragma unroll
    for (int i = 0; i < MI; ++i)
#pragma unroll
        for (int j = 0; j < 4; ++j) acc[i][j] = (f32x4){0.f, 0.f, 0.f, 0.f};

    for (int k0 = 0; k0 < K; k0 += 64) {
        __syncthreads();
#pragma unroll
        for (int p = 0; p < 4; ++p)
            gload_lds16(Ab + (size_t)32 * p * K + k0, AsW + p * 2048);
#pragma unroll
        for (int p = 0; p < BR; ++p)
            gload_lds16(Bb + (size_t)32 * p * K + k0, BsW + p * 2048);
        __syncthreads();
#pragma unroll
        for (int half = 0; half < 2; ++half) {
            const int cb = ((half * 4 + kq) ^ (ln & 7)) * 8;
            bf16x8 bfr[4];
#pragma unroll
            for (int j = 0; j < 4; ++j)
                bfr[j] = *(const bf16x8*)&Bs[(wc + j * 16 + ln) * 64 + cb];
#pragma unroll
            for (int i = 0; i < MI; ++i) {
                const bf16x8 af = *(const bf16x8*)&As[(wr + i * 16 + ln) * 64 + cb];
#pragma unroll
                for (int j = 0; j < 4; ++j)
                    acc[i][j] = __builtin_amdgcn_mfma_f32_16x16x32_bf16(af, bfr[j], acc[i][j], 0, 0, 0);
            }
        }
    }

#pragma unroll
    for (int i = 0; i < MI; ++i) {
        const int rowb = bm + wr + i * 16 + kq * 4;
#pragma unroll
        for (int j = 0; j < 4; ++j) {
            const int colg = bn + wc + j * 16 + ln;
            const float bv = (colg < split) ? bias1[colg] : bias2[colg - split];
            if (vtmode) {
                union { u16x4 v; ushort u[4]; } pk;
#pragma unroll
                for (int rr = 0; rr < 4; ++rr) {
                    float v = acc[i][j][rr] + bv;
                    bf16 t = __float2bfloat16(v);
                    pk.u[rr] = *(ushort*)&t;
                }
                *(u16x4*)((ushort*)Cv + ((size_t)(rowb >> 10) * 512 + colg) * 1024 + (rowb & 1023)) = pk.v;
            } else {
#pragma unroll
                for (int rr = 0; rr < 4; ++rr) {
                    float v = acc[i][j][rr] + bv;
                    if (relu) v = fmaxf(v, 0.f);
                    if (OUTBF16)
                        ((bf16*)Cv)[(size_t)(rowb + rr) * N + colg] = __float2bfloat16(v);
                    else
                        ((float*)Cv)[(size_t)(rowb + rr) * N + colg] = v;
                }
            }
        }
    }
}

// ---------------------------------------------------------------- MFMA flash attention
// (R5 structure: counted-vmcnt pipeline at 4 blocks/CU, LDS = 40960 B)
// R6 addition: Q fragments hoisted to registers (peeled read at kt==0; the
// wgbar memory clobbers otherwise force an LDS re-read every iteration).
__global__ __launch_bounds__(256) void attn_kernel(
    const bf16* __restrict__ QK, const bf16* __restrict__ Vt,
    bf16* __restrict__ Og)
{
    __shared__ ushort Qs[64 * 64];        // 8192 B
    __shared__ ushort Ks[2][64 * 64];     // 16384 B
    __shared__ ushort Vs[64 * 64];        // 8192 B  [dim][key]
    __shared__ ushort Ps[4 * 16 * 64];    // 8192 B  per-wave P, XOR-swizzled

    const int tid = threadIdx.x;
    const int wave = tid >> 6, lane = tid & 63;
    const int ln = lane & 15, kq = lane >> 4;
    const int lin = blockIdx.x + 16 * blockIdx.y;
    const int loc = lin >> 3;
    const int qt = loc & 15;
    const int bh = (lin & 7) + 8 * (loc >> 4);
    const int b = bh >> 3, h = bh & 7;

    const int srow = tid >> 3;                 // 0..31
    const int sgcb = (tid & 7) ^ (srow & 7);
    const ushort* gQ = (const ushort*)QK + (size_t)(b * SEQ + qt * 64 + srow) * 1024 + h * 64 + sgcb * 8;
    const ushort* gK = (const ushort*)QK + (size_t)(b * SEQ + srow) * 1024 + 512 + h * 64 + sgcb * 8;
    const ushort* gV = (const ushort*)Vt + (size_t)(bh * 64 + srow) * 1024 + sgcb * 8;

    // prologue issue order matters for the vmcnt ledger: Q2, V(0)2, K(0)2
    gload_lds16(gQ, Qs + wave * 512);
    gload_lds16(gQ + 32 * 1024, Qs + 2048 + wave * 512);
    gload_lds16(gV, Vs + wave * 512);
    gload_lds16(gV + (size_t)32 * 1024, Vs + 2048 + wave * 512);
    gload_lds16(gK, Ks[0] + wave * 512);
    gload_lds16(gK + (size_t)32 * 1024, Ks[0] + 2048 + wave * 512);

    float rs[4];
    f32x4 oacc[4];
#pragma unroll
    for (int r = 0; r < 4; ++r) { rs[r] = 0.f; oacc[r] = (f32x4){0.f, 0.f, 0.f, 0.f}; }
    const float sc2 = 0.125f * 1.4426950408889634f;   // 1/sqrt(64) * log2(e)

    const int cb0 = (kq ^ (ln & 7)) * 8;
    const int cb1 = ((4 + kq) ^ (ln & 7)) * 8;

    bf16x8 aq0, aq1;   // loop-invariant Q fragments, filled at kt==0

    for (int kt = 0; kt <= qt; ++kt) {
        const int bf = kt & 1;
        if (kt > 0) {
            wgbar();   // barA: all waves done reading Vs (PV kt-1) and Ks[bf^1] (QK^T kt-1)
            const size_t kn = (size_t)kt * 64;
            gload_lds16(gV + kn, Vs + wave * 512);
            gload_lds16(gV + (size_t)32 * 1024 + kn, Vs + 2048 + wave * 512);
        }
        if (kt < qt) {
            const size_t kn1 = (size_t)(kt + 1) * 64;
            gload_lds16(gK + kn1 * 1024, Ks[bf ^ 1] + wave * 512);
            gload_lds16(gK + (kn1 + 32) * 1024, Ks[bf ^ 1] + 2048 + wave * 512);
            if (kt == 0) asm volatile("s_waitcnt vmcnt(2)" ::: "memory");  // drains Q,V(0),K(0); K(1) in flight
            else         asm volatile("s_waitcnt vmcnt(4)" ::: "memory");  // drains K(kt); V(kt)+K(kt+1) in flight
        } else {
            if (kt == 0) asm volatile("s_waitcnt vmcnt(0)" ::: "memory");  // qt==0: drain all
            else         asm volatile("s_waitcnt vmcnt(2)" ::: "memory");  // drains K(qt); V(qt) in flight
        }
        wgbar();   // barB: publish K(kt) (and Q/V(0) at kt==0)

        if (kt == 0) {   // one-time Q fragment load into registers
            aq0 = *(const bf16x8*)&Qs[(wave * 16 + ln) * 64 + cb0];
            aq1 = *(const bf16x8*)&Qs[(wave * 16 + ln) * 64 + cb1];
        }

        // S = Q K^T : per wave 16x64
        f32x4 s[4];
        __builtin_amdgcn_s_setprio(1);
#pragma unroll
        for (int c = 0; c < 4; ++c) {
            const bf16x8 bk0 = *(const bf16x8*)&Ks[bf][(c * 16 + ln) * 64 + cb0];
            const bf16x8 bk1 = *(const bf16x8*)&Ks[bf][(c * 16 + ln) * 64 + cb1];
            s[c] = (f32x4){0.f, 0.f, 0.f, 0.f};
            s[c] = __builtin_amdgcn_mfma_f32_16x16x32_bf16(aq0, bk0, s[c], 0, 0, 0);
            s[c] = __builtin_amdgcn_mfma_f32_16x16x32_bf16(aq1, bk1, s[c], 0, 0, 0);
        }
        __builtin_amdgcn_s_setprio(0);
        // P = exp2(s*sc2) with causal mask on the diagonal tile; no max shift.
        // Swizzled store: row=kq*4+r, blk=(2c+(ln>>3))^(row&7), off=ln&7.
        if (kt == qt) {
#pragma unroll
            for (int c = 0; c < 4; ++c)
#pragma unroll
                for (int r = 0; r < 4; ++r) {
                    const int qg = wave * 16 + kq * 4 + r;
                    const int jg = c * 16 + ln;
                    const float pv = (jg <= qg) ? exp2f(s[c][r] * sc2) : 0.f;
                    rs[r] += pv;
                    const int prow = kq * 4 + r;
                    const int pblk = (2 * c + (ln >> 3)) ^ (prow & 7);
                    *(bf16*)&Ps[wave * 1024 + prow * 64 + pblk * 8 + (ln & 7)] = __float2bfloat16(pv);
                }
        } else {
#pragma unroll
            for (int c = 0; c < 4; ++c)
#pragma unroll
                for (int r = 0; r < 4; ++r) {
                    const float pv = exp2f(s[c][r] * sc2);
                    rs[r] += pv;
                    const int prow = kq * 4 + r;
                    const int pblk = (2 * c + (ln >> 3)) ^ (prow & 7);
                    *(bf16*)&Ps[wave * 1024 + prow * 64 + pblk * 8 + (ln & 7)] = __float2bfloat16(pv);
                }
        }
        // V-wait + publish
        if (kt < qt) asm volatile("s_waitcnt vmcnt(2)" ::: "memory");  // drains V(kt); K(kt+1) in flight
        else         asm volatile("s_waitcnt vmcnt(0)" ::: "memory");
        wgbar();   // barC: publish V(kt)

        // P V (P from LDS in A-layout, swizzled; same-wave RAW)
        const bf16x8 ap0 = *(const bf16x8*)&Ps[wave * 1024 + ln * 64 + ((kq ^ (ln & 7)) << 3)];
        const bf16x8 ap1 = *(const bf16x8*)&Ps[wave * 1024 + ln * 64 + (((4 + kq) ^ (ln & 7)) << 3)];
        __builtin_amdgcn_s_setprio(1);
#pragma unroll
        for (int c2 = 0; c2 < 4; ++c2) {
            const bf16x8 bv0 = *(const bf16x8*)&Vs[(c2 * 16 + ln) * 64 + cb0];
            const bf16x8 bv1 = *(const bf16x8*)&Vs[(c2 * 16 + ln) * 64 + cb1];
            oacc[c2] = __builtin_amdgcn_mfma_f32_16x16x32_bf16(ap0, bv0, oacc[c2], 0, 0, 0);
            oacc[c2] = __builtin_amdgcn_mfma_f32_16x16x32_bf16(ap1, bv1, oacc[c2], 0, 0, 0);
        }
        __builtin_amdgcn_s_setprio(0);
    }
    // single row-sum reduction at the end
    float inv[4];
#pragma unroll
    for (int r = 0; r < 4; ++r) {
        float v = rs[r];
        v += __shfl_xor(v, 1);
        v += __shfl_xor(v, 2);
        v += __shfl_xor(v, 4);
        v += __shfl_xor(v, 8);
        inv[r] = 1.f / v;
    }
#pragma unroll
    for (int c2 = 0; c2 < 4; ++c2)
#pragma unroll
        for (int r = 0; r < 4; ++r)
            Og[(size_t)(b * SEQ + qt * 64 + wave * 16 + kq * 4 + r) * 512 + h * 64 + c2 * 16 + ln]
                = __float2bfloat16(oacc[c2][r] * inv[r]);
}

// ---------------------------------------------------------------- layernorm pair (wave-per-row)
__global__ __launch_bounds__(256) void lnp_kernel(
    const float* __restrict__ x0, const bf16* __restrict__ r0, const float* __restrict__ s0,
    const float* __restrict__ b0, float* __restrict__ of0, bf16* __restrict__ oh0,
    const float* __restrict__ x1, const bf16* __restrict__ r1, const float* __restrict__ s1,
    const float* __restrict__ b1, float* __restrict__ of1, bf16* __restrict__ oh1)
{
    const float* x = x0; const bf16* res = r0; const float* s = s0; const float* bb = b0;
    float* of = of0; bf16* oh = oh0;
    if (blockIdx.y) { x = x1; res = r1; s = s1; bb = b1; of = of1; oh = oh1; }
    const int wave = threadIdx.x >> 6, lane = threadIdx.x & 63;
    const int row = blockIdx.x * 4 + wave;
    const int d0 = lane * 8;
    const size_t o = (size_t)row * DM + d0;

    const float4 xa = *(const float4*)&x[o];
    const float4 xb = *(const float4*)&x[o + 4];
    const bf16x8 rv = *(const bf16x8*)&res[o];
    float v[8];
    v[0] = xa.x + bf2f(rv[0]); v[1] = xa.y + bf2f(rv[1]);
    v[2] = xa.z + bf2f(rv[2]); v[3] = xa.w + bf2f(rv[3]);
    v[4] = xb.x + bf2f(rv[4]); v[5] = xb.y + bf2f(rv[5]);
    v[6] = xb.z + bf2f(rv[6]); v[7] = xb.w + bf2f(rv[7]);

    float sum = 0.f;
#pragma unroll
    for (int j = 0; j < 8; ++j) sum += v[j];
#pragma unroll
    for (int off = 1; off <= 32; off <<= 1) sum += __shfl_xor(sum, off);
    const float mu = sum * (1.f / DM);

    float vs = 0.f;
#pragma unroll
    for (int j = 0; j < 8; ++j) { const float d = v[j] - mu; vs += d * d; }
#pragma unroll
    for (int off = 1; off <= 32; off <<= 1) vs += __shfl_xor(vs, off);
    const float rstd = rsqrtf(vs * (1.f / DM) + 1e-5f);

    const float4 sa = *(const float4*)&s[d0];
    const float4 sb = *(const float4*)&s[d0 + 4];
    const float4 ba = *(const float4*)&bb[d0];
    const float4 b4 = *(const float4*)&bb[d0 + 4];
    float ov[8];
    ov[0] = (v[0] - mu) * rstd * sa.x + ba.x;
    ov[1] = (v[1] - mu) * rstd * sa.y + ba.y;
    ov[2] = (v[2] - mu) * rstd * sa.z + ba.z;
    ov[3] = (v[3] - mu) * rstd * sa.w + ba.w;
    ov[4] = (v[4] - mu) * rstd * sb.x + b4.x;
    ov[5] = (v[5] - mu) * rstd * sb.y + b4.y;
    ov[6] = (v[6] - mu) * rstd * sb.z + b4.z;
    ov[7] = (v[7] - mu) * rstd * sb.w + b4.w;
    *(float4*)&of[o]     = (float4){ov[0], ov[1], ov[2], ov[3]};
    *(float4*)&of[o + 4] = (float4){ov[4], ov[5], ov[6], ov[7]};
    union { bf16x8 vv; ushort u[8]; } pk;
#pragma unroll
    for (int j = 0; j < 8; ++j) { bf16 t = __float2bfloat16(ov[j]); pk.u[j] = *(ushort*)&t; }
    *(bf16x8*)&oh[o] = pk.vv;
}

// ---------------------------------------------------------------- head gather (wave-per-token)
__global__ __launch_bounds__(256) void gather_kernel(
    const bf16* __restrict__ ctx16, const bf16* __restrict__ val16,
    const float* __restrict__ skill, const int* __restrict__ q,
    bf16* __restrict__ feat)
{
    const int wave = threadIdx.x >> 6, lane = threadIdx.x & 63;
    const int t = blockIdx.x * 4 + wave;
    const int d0 = lane * 8;
    const float* sp = skill + (size_t)q[t] * DM + d0;
    bf16* fp = feat + (size_t)t * (3 * DM);
    *(bf16x8*)&fp[d0]      = *(const bf16x8*)&ctx16[(size_t)t * DM + d0];
    *(bf16x8*)&fp[DM + d0] = *(const bf16x8*)&val16[(size_t)t * DM + d0];
    const float4 s4a = *(const float4*)&sp[0];
    const float4 s4b = *(const float4*)&sp[4];
    union { bf16x8 vv; ushort u[8]; } pk;
    const float sv[8] = {s4a.x, s4a.y, s4a.z, s4a.w, s4b.x, s4b.y, s4b.z, s4b.w};
#pragma unroll
    for (int j = 0; j < 8; ++j) { bf16 t2 = __float2bfloat16(sv[j]); pk.u[j] = *(ushort*)&t2; }
    *(bf16x8*)&fp[2 * DM + d0] = pk.vv;
}

// ---------------------------------------------------------------- logits (wave-per-token)
__global__ __launch_bounds__(256) void logits_kernel(
    const float* __restrict__ h2, const float* __restrict__ w,
    const float* __restrict__ bptr, float* __restrict__ out)
{
    const int wave = threadIdx.x >> 6, lane = threadIdx.x & 63;
    const int t = blockIdx.x * 4 + wave;
    const float4 hv = *(const float4*)&h2[(size_t)t * 256 + lane * 4];
    const float4 wv = *(const float4*)&w[lane * 4];
    float sum = hv.x * wv.x + hv.y * wv.y + hv.z * wv.z + hv.w * wv.w;
#pragma unroll
    for (int off = 1; off <= 32; off <<= 1) sum += __shfl_xor(sum, off);
    if (lane == 0) {
        const float logit = sum + bptr[0];
        out[t] = 1.f / (1.f + __expf(-logit));
    }
}

// ---------------------------------------------------------------- launch
extern "C" void kernel_launch(void* const* d_in, const int* in_sizes, int n_in,
                              void* d_out, int out_size, void* d_ws, size_t ws_size,
                              hipStream_t stream)
{
    const int*   q         = (const int*)d_in[0];
    const int*   r         = (const int*)d_in[1];
    const float* ctx_emb   = (const float*)d_in[2];
    const float* val_emb   = (const float*)d_in[3];
    const float* skill_emb = (const float*)d_in[4];
    const float* pos_emb   = (const float*)d_in[5];
    const float* Wq = (const float*)d_in[6];
    const float* bq = (const float*)d_in[7];
    const float* Wk = (const float*)d_in[8];
    const float* bk = (const float*)d_in[9];
    const float* Wv = (const float*)d_in[10];
    const float* bv = (const float*)d_in[11];
    const float* Wo = (const float*)d_in[12];
    const float* bo = (const float*)d_in[13];
    const float* ln1c_s = (const float*)d_in[14];
    const float* ln1c_b = (const float*)d_in[15];
    const float* ln1v_s = (const float*)d_in[16];
    const float* ln1v_b = (const float*)d_in[17];
    const float* ln2c_s = (const float*)d_in[18];
    const float* ln2c_b = (const float*)d_in[19];
    const float* ln2v_s = (const float*)d_in[20];
    const float* ln2v_b = (const float*)d_in[21];
    const float* fc1c_W = (const float*)d_in[22];
    const float* fc1c_b = (const float*)d_in[23];
    const float* fc2c_W = (const float*)d_in[24];
    const float* fc2c_b = (const float*)d_in[25];
    const float* fc1v_W = (const float*)d_in[26];
    const float* fc1v_b = (const float*)d_in[27];
    const float* fc2v_W = (const float*)d_in[28];
    const float* fc2v_b = (const float*)d_in[29];
    const float* hW1 = (const float*)d_in[30];
    const float* hb1 = (const float*)d_in[31];
    const float* hW2 = (const float*)d_in[32];
    const float* hb2 = (const float*)d_in[33];
    const float* hW3 = (const float*)d_in[34];
    const float* hb3 = (const float*)d_in[35];
    float* out = (float*)d_out;

    char* p = (char*)d_ws;
    auto alloc = [&](size_t bytes) { char* ret = p; p += bytes; return ret; };
    float* ctx32 = (float*)alloc(16777216);
    float* val32 = (float*)alloc(16777216);
    bf16*  ob16c = (bf16*)alloc(8388608);
    bf16*  ob16v = (bf16*)alloc(8388608);
    bf16*  ctx16 = (bf16*)alloc(8388608);
    bf16*  val16 = (bf16*)alloc(8388608);
    bf16*  qk16  = (bf16*)alloc(16777216);   // A: [8192][1024]
    bf16*  v16pad= (bf16*)alloc(8388608);    // B: dead (alias sizing)
    bf16*  vt16  = (bf16*)alloc(8388608);    // C: [(b*8+h)*64+d][1024]
    bf16*  att16 = (bf16*)alloc(8388608);    // D
    bf16*  mid16c = (bf16*)alloc(33554432);  // [8192][2048]
    bf16*  qkT   = (bf16*)alloc(4194304);
    bf16*  vT    = (bf16*)alloc(2097152);
    bf16*  oT    = (bf16*)alloc(2097152);
    bf16*  fc1cT = (bf16*)alloc(8388608);
    bf16*  fc2cT = (bf16*)alloc(8388608);
    bf16*  fc1vT = (bf16*)alloc(8388608);
    bf16*  fc2vT = (bf16*)alloc(8388608);
    bf16*  hW1T  = (bf16*)alloc(6291456);
    bf16*  hW2T  = (bf16*)alloc(1048576);
    (void)v16pad;
    // aliases (liveness-checked):
    bf16*  mid16v = qk16;                    // dead during FFN
    bf16*  feat16 = qk16;                    // post-loop
    float* h2     = (float*)vt16;            // post-loop

    const dim3 tb(32, 8);
    // merged weight transposes (z pairs): Wq+Wk -> qkT, Wv+Wo -> vT/oT,
    // fc1c+fc1v, fc2c+fc2v; heads separate.
    transpose_pair_kernel<<<dim3(16, 16, 8), tb, 0, stream>>>(
        Wq, Wk, qkT, qkT + 262144, 512, 512, 262144, 524288, 4);
    transpose_pair_kernel<<<dim3(16, 16, 8), tb, 0, stream>>>(
        Wv, Wo, vT, oT, 512, 512, 262144, 262144, 4);
    transpose_pair_kernel<<<dim3(64, 16, 8), tb, 0, stream>>>(
        fc1c_W, fc1v_W, fc1cT, fc1vT, 512, 2048, 1048576, 1048576, 4);
    transpose_pair_kernel<<<dim3(16, 64, 8), tb, 0, stream>>>(
        fc2c_W, fc2v_W, fc2cT, fc2vT, 2048, 512, 1048576, 1048576, 4);
    transpose_pair_kernel<<<dim3(64, 48, 1), tb, 0, stream>>>(
        hW1, hW1, hW1T, hW1T, 1536, 2048, 0, 0, 1);
    transpose_pair_kernel<<<dim3(8, 64, 1), tb, 0, stream>>>(
        hW2, hW2, hW2T, hW2T, 2048, 256, 0, 0, 1);

    embed_kernel<<<TOK / 4, 256, 0, stream>>>(q, r, ctx_emb, val_emb, pos_emb,
                                              ctx32, val32, ctx16, val16);

    for (int i = 0; i < NBLK; ++i) {
        // merged QK (z=0, N=1024) + V (z=1, N=512, vt-layout; bn>=512 blocks exit)
        mfma_gemm<128, true><<<dim3(8, 64, 2), 256, 0, stream>>>(
            (const ushort*)ctx16, (const ushort*)(qkT + (size_t)i * 524288),
            bq + i * DM, bk + i * DM, 512, qk16, 1024, 512, 0, 0,
            (const ushort*)val16, (const ushort*)(vT + (size_t)i * 262144),
            bv + i * DM, vt16, 512, 1);
        attn_kernel<<<dim3(16, 64), 256, 0, stream>>>(qk16, vt16, att16);
        mfma_gemm<64, true><<<dim3(8, 64), 256, 0, stream>>>(
            (const ushort*)att16, (const ushort*)(oT + (size_t)i * 262144),
            bo + i * DM, nullptr, 1 << 30, ob16c, 512, 512, 0, 0,
            nullptr, nullptr, nullptr, nullptr, 512, 0);
        lnp_kernel<<<dim3(TOK / 4, 2), 256, 0, stream>>>(
            ctx32, ob16c, ln1c_s + i * DM, ln1c_b + i * DM, ctx32, ctx16,
            val32, ob16c, ln1v_s + i * DM, ln1v_b + i * DM, val32, val16);
        mfma_gemm<128, true><<<dim3(16, 64, 2), 256, 0, stream>>>(
            (const ushort*)ctx16, (const ushort*)(fc1cT + (size_t)i * 1048576),
            fc1c_b + i * DFFN, nullptr, 1 << 30, mid16c, 2048, 512, 1, 0,
            (const ushort*)val16, (const ushort*)(fc1vT + (size_t)i * 1048576),
            fc1v_b + i * DFFN, mid16v, 2048, 0);
        mfma_gemm<128, true><<<dim3(4, 64, 2), 256, 0, stream>>>(
            (const ushort*)mid16c, (const ushort*)(fc2cT + (size_t)i * 1048576),
            fc2c_b + i * DM, nullptr, 1 << 30, ob16c, 512, 2048, 0, 0,
            (const ushort*)mid16v, (const ushort*)(fc2vT + (size_t)i * 1048576),
            fc2v_b + i * DM, ob16v, 512, 0);
        lnp_kernel<<<dim3(TOK / 4, 2), 256, 0, stream>>>(
            ctx32, ob16c, ln2c_s + i * DM, ln2c_b + i * DM, ctx32, ctx16,
            val32, ob16v, ln2v_s + i * DM, ln2v_b + i * DM, val32, val16);
    }

    gather_kernel<<<TOK / 4, 256, 0, stream>>>(ctx16, val16, skill_emb, q, feat16);
    mfma_gemm<128, true><<<dim3(16, 64), 256, 0, stream>>>(
        (const ushort*)feat16, (const ushort*)hW1T, hb1, nullptr, 1 << 30, mid16c, 2048, 1536, 1, 0,
        nullptr, nullptr, nullptr, nullptr, 2048, 0);
    mfma_gemm<64, false><<<dim3(4, 64), 256, 0, stream>>>(
        (const ushort*)mid16c, (const ushort*)hW2T, hb2, nullptr, 1 << 30, h2, 256, 2048, 1, 0,
        nullptr, nullptr, nullptr, nullptr, 256, 0);
    logits_kernel<<<TOK / 4, 256, 0, stream>>>(h2, hW3, hb3, out);
}

// Round 8
// 1075.267 us; speedup vs baseline: 1.0180x; 1.0180x over previous
//
#include <hip/hip_runtime.h>
#include <hip/hip_bf16.h>
#include <math.h>

#define TOK 8192   // B*L
#define DM 512
#define NH 8
#define DKH 64
#define DFFN 2048
#define SEQ 1024
#define NBLK 4
#define NUMC 1000

typedef __attribute__((ext_vector_type(8))) short bf16x8;
typedef __attribute__((ext_vector_type(4))) float f32x4;
typedef __attribute__((ext_vector_type(4))) ushort u16x4;
typedef __hip_bfloat16 bf16;

__device__ __forceinline__ void gload_lds16(const ushort* g, ushort* l) {
    __builtin_amdgcn_global_load_lds(
        (const __attribute__((address_space(1))) void*)g,
        (__attribute__((address_space(3))) void*)l, 16, 0, 0);
}

// raw workgroup barrier WITHOUT the compiler's vmcnt(0)/lgkmcnt(0) drain;
// empty asm = compiler-level memory fence so LDS ops can't migrate across.
__device__ __forceinline__ void wgbar() {
    asm volatile("" ::: "memory");
    __builtin_amdgcn_s_barrier();
    asm volatile("" ::: "memory");
}

__device__ __forceinline__ float bf2f(short u) {
    return __uint_as_float((unsigned)(unsigned short)u << 16);
}

// ---------------------------------------------------------------- embed (wave-per-token, vectorized)
__global__ __launch_bounds__(256) void embed_kernel(
    const int* __restrict__ q, const int* __restrict__ r,
    const float* __restrict__ ctx_emb, const float* __restrict__ val_emb,
    const float* __restrict__ pos_emb,
    float* __restrict__ ctx32, float* __restrict__ val32,
    bf16* __restrict__ ctx16, bf16* __restrict__ val16)
{
    const int wave = threadIdx.x >> 6, lane = threadIdx.x & 63;
    const int t = blockIdx.x * 4 + wave;
    const int inter = q[t] + NUMC * r[t];
    const int l = t & (SEQ - 1);
    const int d0 = lane * 8;
    const float* ce = ctx_emb + (size_t)inter * DM + d0;
    const float* ve = val_emb + (size_t)inter * DM + d0;
    const float* pe = pos_emb + (size_t)l * DM + d0;
    const size_t o = (size_t)t * DM + d0;
    float c[8], v[8];
#pragma unroll
    for (int j = 0; j < 8; j += 4) {
        const float4 pv = *(const float4*)&pe[j];
        const float4 cv = *(const float4*)&ce[j];
        const float4 vv = *(const float4*)&ve[j];
        c[j] = cv.x + pv.x; c[j+1] = cv.y + pv.y; c[j+2] = cv.z + pv.z; c[j+3] = cv.w + pv.w;
        v[j] = vv.x + pv.x; v[j+1] = vv.y + pv.y; v[j+2] = vv.z + pv.z; v[j+3] = vv.w + pv.w;
        *(float4*)&ctx32[o + j] = (float4){c[j], c[j+1], c[j+2], c[j+3]};
        *(float4*)&val32[o + j] = (float4){v[j], v[j+1], v[j+2], v[j+3]};
    }
    union { bf16x8 vv; ushort u[8]; } pc, pv2;
#pragma unroll
    for (int j = 0; j < 8; ++j) {
        bf16 tc = __float2bfloat16(c[j]); pc.u[j] = *(ushort*)&tc;
        bf16 tv = __float2bfloat16(v[j]); pv2.u[j] = *(ushort*)&tv;
    }
    *(bf16x8*)&ctx16[o] = pc.vv;
    *(bf16x8*)&val16[o] = pv2.vv;
}

// ---------------------------------------------------------------- transpose+cvt (weight pairs via z)
__global__ __launch_bounds__(256) void transpose_pair_kernel(
    const float* __restrict__ srcA, const float* __restrict__ srcB,
    bf16* __restrict__ dstA, bf16* __restrict__ dstB,
    int K, int N, long sb, long db, int zsplit)
{
    __shared__ float t[32][33];
    const int z = blockIdx.z;
    const float* src; bf16* dst;
    if (z < zsplit) { src = srcA + (long)z * sb;            dst = dstA + (long)z * db; }
    else            { src = srcB + (long)(z - zsplit) * sb; dst = dstB + (long)(z - zsplit) * db; }
    const int n0 = blockIdx.x * 32;
    const int k0 = blockIdx.y * 32;
    const int tx = threadIdx.x;
    const int ty = threadIdx.y;
    for (int i = ty; i < 32; i += 8) t[i][tx] = src[(size_t)(k0 + i) * N + n0 + tx];
    __syncthreads();
    for (int i = ty; i < 32; i += 8)
        dst[(size_t)(n0 + i) * K + k0 + tx] = __float2bfloat16(t[tx][i]);
}

// ---------------------------------------------------------------- MFMA GEMM (128-tile, R5 structure)
// blockIdx.z==1 selects the second problem (A1/Bt1/bias1_1/Cv1) with its own
// N (Nz) and vtmode (vtz), split forced to 1<<30; blocks whose bn >= N exit.
template<int BN, bool OUTBF16>
__global__ __launch_bounds__(256, 3) void mfma_gemm(
    const ushort* __restrict__ A, const ushort* __restrict__ Bt,
    const float* __restrict__ bias1, const float* __restrict__ bias2, int split,
    void* __restrict__ Cv, int N, int K, int relu, int vtmode,
    const ushort* __restrict__ A1, const ushort* __restrict__ Bt1,
    const float* __restrict__ bias1_1, void* __restrict__ Cv1,
    int Nz, int vtz)
{
    if (blockIdx.z) { A = A1; Bt = Bt1; bias1 = bias1_1; Cv = Cv1; N = Nz; vtmode = vtz; split = 1 << 30; }
    constexpr int MI = (BN == 128) ? 4 : 2;
    constexpr int BR = BN / 32;
    __shared__ ushort As[128 * 64];
    __shared__ ushort Bs[BN * 64];
    const int tid = threadIdx.x;
    const int wave = tid >> 6;
    const int lane = tid & 63;
    const int ln = lane & 15;
    const int kq = lane >> 4;
    const int nx = gridDim.x;
    const int lin = blockIdx.x + nx * blockIdx.y;
    const int loc = lin >> 3;
    const int mdiv = loc / nx;
    const int bm = ((lin & 7) + 8 * mdiv) * 128;
    const int bn = (loc - mdiv * nx) * BN;
    if (bn >= N) return;   // idle column (merged-dispatch padding); block-uniform
    const int wr = (BN == 128) ? (wave >> 1) * 64 : wave * 32;
    const int wc = (BN == 128) ? (wave & 1) * 64 : 0;

    const int trow = tid >> 3;
    const int gcb = (tid & 7) ^ (trow & 7);
    const ushort* Ab = A + (size_t)(bm + trow) * K + gcb * 8;
    const ushort* Bb = Bt + (size_t)(bn + trow) * K + gcb * 8;
    ushort* AsW = As + wave * 512;
    ushort* BsW = Bs + wave * 512;

    f32x4 acc[MI][4];
#pragma unroll
    for (int i = 0; i < MI; ++i)
#pragma unroll
        for (int j = 0; j < 4; ++j) acc[i][j] = (f32x4){0.f, 0.f, 0.f, 0.f};

    for (int k0 = 0; k0 < K; k0 += 64) {
        __syncthreads();
#pragma unroll
        for (int p = 0; p < 4; ++p)
            gload_lds16(Ab + (size_t)32 * p * K + k0, AsW + p * 2048);
#pragma unroll
        for (int p = 0; p < BR; ++p)
            gload_lds16(Bb + (size_t)32 * p * K + k0, BsW + p * 2048);
        __syncthreads();
#pragma unroll
        for (int half = 0; half < 2; ++half) {
            const int cb = ((half * 4 + kq) ^ (ln & 7)) * 8;
            bf16x8 bfr[4];
#pragma unroll
            for (int j = 0; j < 4; ++j)
                bfr[j] = *(const bf16x8*)&Bs[(wc + j * 16 + ln) * 64 + cb];
#pragma unroll
            for (int i = 0; i < MI; ++i) {
                const bf16x8 af = *(const bf16x8*)&As[(wr + i * 16 + ln) * 64 + cb];
#pragma unroll
                for (int j = 0; j < 4; ++j)
                    acc[i][j] = __builtin_amdgcn_mfma_f32_16x16x32_bf16(af, bfr[j], acc[i][j], 0, 0, 0);
            }
        }
    }

#pragma unroll
    for (int i = 0; i < MI; ++i) {
        const int rowb = bm + wr + i * 16 + kq * 4;
#pragma unroll
        for (int j = 0; j < 4; ++j) {
            const int colg = bn + wc + j * 16 + ln;
            const float bv = (colg < split) ? bias1[colg] : bias2[colg - split];
            if (vtmode) {
                union { u16x4 v; ushort u[4]; } pk;
#pragma unroll
                for (int rr = 0; rr < 4; ++rr) {
                    float v = acc[i][j][rr] + bv;
                    bf16 t = __float2bfloat16(v);
                    pk.u[rr] = *(ushort*)&t;
                }
                *(u16x4*)((ushort*)Cv + ((size_t)(rowb >> 10) * 512 + colg) * 1024 + (rowb & 1023)) = pk.v;
            } else {
#pragma unroll
                for (int rr = 0; rr < 4; ++rr) {
                    float v = acc[i][j][rr] + bv;
                    if (relu) v = fmaxf(v, 0.f);
                    if (OUTBF16)
                        ((bf16*)Cv)[(size_t)(rowb + rr) * N + colg] = __float2bfloat16(v);
                    else
                        ((float*)Cv)[(size_t)(rowb + rr) * N + colg] = v;
                }
            }
        }
    }
}

// ---------------------------------------------------------------- MFMA flash attention
// (R5 structure: counted-vmcnt pipeline at 4 blocks/CU, LDS = 40960 B;
//  R6: Q fragments hoisted to registers)
// R7: load-balanced block->(qt,bh) decode. Work per block ~ qt+1; the old
// decode gave blocks n, n+256, n+512, n+768 IDENTICAL qt, so a CU's 4
// resident blocks were all-heavy or all-light (worst CU: 64 kt-iters vs 34
// balanced). New decode pairs complementary q-tiles in launch order
// (bijective over (qt,bh); kernel body untouched -> bit-identical output).
__global__ __launch_bounds__(256) void attn_kernel(
    const bf16* __restrict__ QK, const bf16* __restrict__ Vt,
    bf16* __restrict__ Og)
{
    __shared__ ushort Qs[64 * 64];        // 8192 B
    __shared__ ushort Ks[2][64 * 64];     // 16384 B
    __shared__ ushort Vs[64 * 64];        // 8192 B  [dim][key]
    __shared__ ushort Ps[4 * 16 * 64];    // 8192 B  per-wave P, XOR-swizzled

    const int tid = threadIdx.x;
    const int wave = tid >> 6, lane = tid & 63;
    const int ln = lane & 15, kq = lane >> 4;
    const int lin = blockIdx.x + 16 * blockIdx.y;
    const int loc = lin >> 3;             // [0,128)
    const int hi = loc >> 5, low = loc & 31;
    const int qt = (hi & 1) ? (15 - (low & 15)) : (low & 15);
    const int bh = (lin & 7) + 8 * ((hi & 1) * 4 + (hi >> 1) * 2 + (low >> 4));
    const int b = bh >> 3, h = bh & 7;

    const int srow = tid >> 3;                 // 0..31
    const int sgcb = (tid & 7) ^ (srow & 7);
    const ushort* gQ = (const ushort*)QK + (size_t)(b * SEQ + qt * 64 + srow) * 1024 + h * 64 + sgcb * 8;
    const ushort* gK = (const ushort*)QK + (size_t)(b * SEQ + srow) * 1024 + 512 + h * 64 + sgcb * 8;
    const ushort* gV = (const ushort*)Vt + (size_t)(bh * 64 + srow) * 1024 + sgcb * 8;

    // prologue issue order matters for the vmcnt ledger: Q2, V(0)2, K(0)2
    gload_lds16(gQ, Qs + wave * 512);
    gload_lds16(gQ + 32 * 1024, Qs + 2048 + wave * 512);
    gload_lds16(gV, Vs + wave * 512);
    gload_lds16(gV + (size_t)32 * 1024, Vs + 2048 + wave * 512);
    gload_lds16(gK, Ks[0] + wave * 512);
    gload_lds16(gK + (size_t)32 * 1024, Ks[0] + 2048 + wave * 512);

    float rs[4];
    f32x4 oacc[4];
#pragma unroll
    for (int r = 0; r < 4; ++r) { rs[r] = 0.f; oacc[r] = (f32x4){0.f, 0.f, 0.f, 0.f}; }
    const float sc2 = 0.125f * 1.4426950408889634f;   // 1/sqrt(64) * log2(e)

    const int cb0 = (kq ^ (ln & 7)) * 8;
    const int cb1 = ((4 + kq) ^ (ln & 7)) * 8;

    bf16x8 aq0, aq1;   // loop-invariant Q fragments, filled at kt==0

    for (int kt = 0; kt <= qt; ++kt) {
        const int bf = kt & 1;
        if (kt > 0) {
            wgbar();   // barA: all waves done reading Vs (PV kt-1) and Ks[bf^1] (QK^T kt-1)
            const size_t kn = (size_t)kt * 64;
            gload_lds16(gV + kn, Vs + wave * 512);
            gload_lds16(gV + (size_t)32 * 1024 + kn, Vs + 2048 + wave * 512);
        }
        if (kt < qt) {
            const size_t kn1 = (size_t)(kt + 1) * 64;
            gload_lds16(gK + kn1 * 1024, Ks[bf ^ 1] + wave * 512);
            gload_lds16(gK + (kn1 + 32) * 1024, Ks[bf ^ 1] + 2048 + wave * 512);
            if (kt == 0) asm volatile("s_waitcnt vmcnt(2)" ::: "memory");  // drains Q,V(0),K(0); K(1) in flight
            else         asm volatile("s_waitcnt vmcnt(4)" ::: "memory");  // drains K(kt); V(kt)+K(kt+1) in flight
        } else {
            if (kt == 0) asm volatile("s_waitcnt vmcnt(0)" ::: "memory");  // qt==0: drain all
            else         asm volatile("s_waitcnt vmcnt(2)" ::: "memory");  // drains K(qt); V(qt) in flight
        }
        wgbar();   // barB: publish K(kt) (and Q/V(0) at kt==0)

        if (kt == 0) {   // one-time Q fragment load into registers
            aq0 = *(const bf16x8*)&Qs[(wave * 16 + ln) * 64 + cb0];
            aq1 = *(const bf16x8*)&Qs[(wave * 16 + ln) * 64 + cb1];
        }

        // S = Q K^T : per wave 16x64
        f32x4 s[4];
        __builtin_amdgcn_s_setprio(1);
#pragma unroll
        for (int c = 0; c < 4; ++c) {
            const bf16x8 bk0 = *(const bf16x8*)&Ks[bf][(c * 16 + ln) * 64 + cb0];
            const bf16x8 bk1 = *(const bf16x8*)&Ks[bf][(c * 16 + ln) * 64 + cb1];
            s[c] = (f32x4){0.f, 0.f, 0.f, 0.f};
            s[c] = __builtin_amdgcn_mfma_f32_16x16x32_bf16(aq0, bk0, s[c], 0, 0, 0);
            s[c] = __builtin_amdgcn_mfma_f32_16x16x32_bf16(aq1, bk1, s[c], 0, 0, 0);
        }
        __builtin_amdgcn_s_setprio(0);
        // P = exp2(s*sc2) with causal mask on the diagonal tile; no max shift.
        // Swizzled store: row=kq*4+r, blk=(2c+(ln>>3))^(row&7), off=ln&7.
        if (kt == qt) {
#pragma unroll
            for (int c = 0; c < 4; ++c)
#pragma unroll
                for (int r = 0; r < 4; ++r) {
                    const int qg = wave * 16 + kq * 4 + r;
                    const int jg = c * 16 + ln;
                    const float pv = (jg <= qg) ? exp2f(s[c][r] * sc2) : 0.f;
                    rs[r] += pv;
                    const int prow = kq * 4 + r;
                    const int pblk = (2 * c + (ln >> 3)) ^ (prow & 7);
                    *(bf16*)&Ps[wave * 1024 + prow * 64 + pblk * 8 + (ln & 7)] = __float2bfloat16(pv);
                }
        } else {
#pragma unroll
            for (int c = 0; c < 4; ++c)
#pragma unroll
                for (int r = 0; r < 4; ++r) {
                    const float pv = exp2f(s[c][r] * sc2);
                    rs[r] += pv;
                    const int prow = kq * 4 + r;
                    const int pblk = (2 * c + (ln >> 3)) ^ (prow & 7);
                    *(bf16*)&Ps[wave * 1024 + prow * 64 + pblk * 8 + (ln & 7)] = __float2bfloat16(pv);
                }
        }
        // V-wait + publish
        if (kt < qt) asm volatile("s_waitcnt vmcnt(2)" ::: "memory");  // drains V(kt); K(kt+1) in flight
        else         asm volatile("s_waitcnt vmcnt(0)" ::: "memory");
        wgbar();   // barC: publish V(kt)

        // P V (P from LDS in A-layout, swizzled; same-wave RAW)
        const bf16x8 ap0 = *(const bf16x8*)&Ps[wave * 1024 + ln * 64 + ((kq ^ (ln & 7)) << 3)];
        const bf16x8 ap1 = *(const bf16x8*)&Ps[wave * 1024 + ln * 64 + (((4 + kq) ^ (ln & 7)) << 3)];
        __builtin_amdgcn_s_setprio(1);
#pragma unroll
        for (int c2 = 0; c2 < 4; ++c2) {
            const bf16x8 bv0 = *(const bf16x8*)&Vs[(c2 * 16 + ln) * 64 + cb0];
            const bf16x8 bv1 = *(const bf16x8*)&Vs[(c2 * 16 + ln) * 64 + cb1];
            oacc[c2] = __builtin_amdgcn_mfma_f32_16x16x32_bf16(ap0, bv0, oacc[c2], 0, 0, 0);
            oacc[c2] = __builtin_amdgcn_mfma_f32_16x16x32_bf16(ap1, bv1, oacc[c2], 0, 0, 0);
        }
        __builtin_amdgcn_s_setprio(0);
    }
    // single row-sum reduction at the end
    float inv[4];
#pragma unroll
    for (int r = 0; r < 4; ++r) {
        float v = rs[r];
        v += __shfl_xor(v, 1);
        v += __shfl_xor(v, 2);
        v += __shfl_xor(v, 4);
        v += __shfl_xor(v, 8);
        inv[r] = 1.f / v;
    }
#pragma unroll
    for (int c2 = 0; c2 < 4; ++c2)
#pragma unroll
        for (int r = 0; r < 4; ++r)
            Og[(size_t)(b * SEQ + qt * 64 + wave * 16 + kq * 4 + r) * 512 + h * 64 + c2 * 16 + ln]
                = __float2bfloat16(oacc[c2][r] * inv[r]);
}

// ---------------------------------------------------------------- layernorm pair (wave-per-row)
__global__ __launch_bounds__(256) void lnp_kernel(
    const float* __restrict__ x0, const bf16* __restrict__ r0, const float* __restrict__ s0,
    const float* __restrict__ b0, float* __restrict__ of0, bf16* __restrict__ oh0,
    const float* __restrict__ x1, const bf16* __restrict__ r1, const float* __restrict__ s1,
    const float* __restrict__ b1, float* __restrict__ of1, bf16* __restrict__ oh1)
{
    const float* x = x0; const bf16* res = r0; const float* s = s0; const float* bb = b0;
    float* of = of0; bf16* oh = oh0;
    if (blockIdx.y) { x = x1; res = r1; s = s1; bb = b1; of = of1; oh = oh1; }
    const int wave = threadIdx.x >> 6, lane = threadIdx.x & 63;
    const int row = blockIdx.x * 4 + wave;
    const int d0 = lane * 8;
    const size_t o = (size_t)row * DM + d0;

    const float4 xa = *(const float4*)&x[o];
    const float4 xb = *(const float4*)&x[o + 4];
    const bf16x8 rv = *(const bf16x8*)&res[o];
    float v[8];
    v[0] = xa.x + bf2f(rv[0]); v[1] = xa.y + bf2f(rv[1]);
    v[2] = xa.z + bf2f(rv[2]); v[3] = xa.w + bf2f(rv[3]);
    v[4] = xb.x + bf2f(rv[4]); v[5] = xb.y + bf2f(rv[5]);
    v[6] = xb.z + bf2f(rv[6]); v[7] = xb.w + bf2f(rv[7]);

    float sum = 0.f;
#pragma unroll
    for (int j = 0; j < 8; ++j) sum += v[j];
#pragma unroll
    for (int off = 1; off <= 32; off <<= 1) sum += __shfl_xor(sum, off);
    const float mu = sum * (1.f / DM);

    float vs = 0.f;
#pragma unroll
    for (int j = 0; j < 8; ++j) { const float d = v[j] - mu; vs += d * d; }
#pragma unroll
    for (int off = 1; off <= 32; off <<= 1) vs += __shfl_xor(vs, off);
    const float rstd = rsqrtf(vs * (1.f / DM) + 1e-5f);

    const float4 sa = *(const float4*)&s[d0];
    const float4 sb = *(const float4*)&s[d0 + 4];
    const float4 ba = *(const float4*)&bb[d0];
    const float4 b4 = *(const float4*)&bb[d0 + 4];
    float ov[8];
    ov[0] = (v[0] - mu) * rstd * sa.x + ba.x;
    ov[1] = (v[1] - mu) * rstd * sa.y + ba.y;
    ov[2] = (v[2] - mu) * rstd * sa.z + ba.z;
    ov[3] = (v[3] - mu) * rstd * sa.w + ba.w;
    ov[4] = (v[4] - mu) * rstd * sb.x + b4.x;
    ov[5] = (v[5] - mu) * rstd * sb.y + b4.y;
    ov[6] = (v[6] - mu) * rstd * sb.z + b4.z;
    ov[7] = (v[7] - mu) * rstd * sb.w + b4.w;
    *(float4*)&of[o]     = (float4){ov[0], ov[1], ov[2], ov[3]};
    *(float4*)&of[o + 4] = (float4){ov[4], ov[5], ov[6], ov[7]};
    union { bf16x8 vv; ushort u[8]; } pk;
#pragma unroll
    for (int j = 0; j < 8; ++j) { bf16 t = __float2bfloat16(ov[j]); pk.u[j] = *(ushort*)&t; }
    *(bf16x8*)&oh[o] = pk.vv;
}

// ---------------------------------------------------------------- head gather (wave-per-token)
__global__ __launch_bounds__(256) void gather_kernel(
    const bf16* __restrict__ ctx16, const bf16* __restrict__ val16,
    const float* __restrict__ skill, const int* __restrict__ q,
    bf16* __restrict__ feat)
{
    const int wave = threadIdx.x >> 6, lane = threadIdx.x & 63;
    const int t = blockIdx.x * 4 + wave;
    const int d0 = lane * 8;
    const float* sp = skill + (size_t)q[t] * DM + d0;
    bf16* fp = feat + (size_t)t * (3 * DM);
    *(bf16x8*)&fp[d0]      = *(const bf16x8*)&ctx16[(size_t)t * DM + d0];
    *(bf16x8*)&fp[DM + d0] = *(const bf16x8*)&val16[(size_t)t * DM + d0];
    const float4 s4a = *(const float4*)&sp[0];
    const float4 s4b = *(const float4*)&sp[4];
    union { bf16x8 vv; ushort u[8]; } pk;
    const float sv[8] = {s4a.x, s4a.y, s4a.z, s4a.w, s4b.x, s4b.y, s4b.z, s4b.w};
#pragma unroll
    for (int j = 0; j < 8; ++j) { bf16 t2 = __float2bfloat16(sv[j]); pk.u[j] = *(ushort*)&t2; }
    *(bf16x8*)&fp[2 * DM + d0] = pk.vv;
}

// ---------------------------------------------------------------- logits (wave-per-token)
__global__ __launch_bounds__(256) void logits_kernel(
    const float* __restrict__ h2, const float* __restrict__ w,
    const float* __restrict__ bptr, float* __restrict__ out)
{
    const int wave = threadIdx.x >> 6, lane = threadIdx.x & 63;
    const int t = blockIdx.x * 4 + wave;
    const float4 hv = *(const float4*)&h2[(size_t)t * 256 + lane * 4];
    const float4 wv = *(const float4*)&w[lane * 4];
    float sum = hv.x * wv.x + hv.y * wv.y + hv.z * wv.z + hv.w * wv.w;
#pragma unroll
    for (int off = 1; off <= 32; off <<= 1) sum += __shfl_xor(sum, off);
    if (lane == 0) {
        const float logit = sum + bptr[0];
        out[t] = 1.f / (1.f + __expf(-logit));
    }
}

// ---------------------------------------------------------------- launch
extern "C" void kernel_launch(void* const* d_in, const int* in_sizes, int n_in,
                              void* d_out, int out_size, void* d_ws, size_t ws_size,
                              hipStream_t stream)
{
    const int*   q         = (const int*)d_in[0];
    const int*   r         = (const int*)d_in[1];
    const float* ctx_emb   = (const float*)d_in[2];
    const float* val_emb   = (const float*)d_in[3];
    const float* skill_emb = (const float*)d_in[4];
    const float* pos_emb   = (const float*)d_in[5];
    const float* Wq = (const float*)d_in[6];
    const float* bq = (const float*)d_in[7];
    const float* Wk = (const float*)d_in[8];
    const float* bk = (const float*)d_in[9];
    const float* Wv = (const float*)d_in[10];
    const float* bv = (const float*)d_in[11];
    const float* Wo = (const float*)d_in[12];
    const float* bo = (const float*)d_in[13];
    const float* ln1c_s = (const float*)d_in[14];
    const float* ln1c_b = (const float*)d_in[15];
    const float* ln1v_s = (const float*)d_in[16];
    const float* ln1v_b = (const float*)d_in[17];
    const float* ln2c_s = (const float*)d_in[18];
    const float* ln2c_b = (const float*)d_in[19];
    const float* ln2v_s = (const float*)d_in[20];
    const float* ln2v_b = (const float*)d_in[21];
    const float* fc1c_W = (const float*)d_in[22];
    const float* fc1c_b = (const float*)d_in[23];
    const float* fc2c_W = (const float*)d_in[24];
    const float* fc2c_b = (const float*)d_in[25];
    const float* fc1v_W = (const float*)d_in[26];
    const float* fc1v_b = (const float*)d_in[27];
    const float* fc2v_W = (const float*)d_in[28];
    const float* fc2v_b = (const float*)d_in[29];
    const float* hW1 = (const float*)d_in[30];
    const float* hb1 = (const float*)d_in[31];
    const float* hW2 = (const float*)d_in[32];
    const float* hb2 = (const float*)d_in[33];
    const float* hW3 = (const float*)d_in[34];
    const float* hb3 = (const float*)d_in[35];
    float* out = (float*)d_out;

    char* p = (char*)d_ws;
    auto alloc = [&](size_t bytes) { char* ret = p; p += bytes; return ret; };
    float* ctx32 = (float*)alloc(16777216);
    float* val32 = (float*)alloc(16777216);
    bf16*  ob16c = (bf16*)alloc(8388608);
    bf16*  ob16v = (bf16*)alloc(8388608);
    bf16*  ctx16 = (bf16*)alloc(8388608);
    bf16*  val16 = (bf16*)alloc(8388608);
    bf16*  qk16  = (bf16*)alloc(16777216);   // A: [8192][1024]
    bf16*  v16pad= (bf16*)alloc(8388608);    // B: dead (alias sizing)
    bf16*  vt16  = (bf16*)alloc(8388608);    // C: [(b*8+h)*64+d][1024]
    bf16*  att16 = (bf16*)alloc(8388608);    // D
    bf16*  mid16c = (bf16*)alloc(33554432);  // [8192][2048]
    bf16*  qkT   = (bf16*)alloc(4194304);
    bf16*  vT    = (bf16*)alloc(2097152);
    bf16*  oT    = (bf16*)alloc(2097152);
    bf16*  fc1cT = (bf16*)alloc(8388608);
    bf16*  fc2cT = (bf16*)alloc(8388608);
    bf16*  fc1vT = (bf16*)alloc(8388608);
    bf16*  fc2vT = (bf16*)alloc(8388608);
    bf16*  hW1T  = (bf16*)alloc(6291456);
    bf16*  hW2T  = (bf16*)alloc(1048576);
    (void)v16pad;
    // aliases (liveness-checked):
    bf16*  mid16v = qk16;                    // dead during FFN
    bf16*  feat16 = qk16;                    // post-loop
    float* h2     = (float*)vt16;            // post-loop

    const dim3 tb(32, 8);
    // merged weight transposes (z pairs): Wq+Wk -> qkT, Wv+Wo -> vT/oT,
    // fc1c+fc1v, fc2c+fc2v; heads separate.
    transpose_pair_kernel<<<dim3(16, 16, 8), tb, 0, stream>>>(
        Wq, Wk, qkT, qkT + 262144, 512, 512, 262144, 524288, 4);
    transpose_pair_kernel<<<dim3(16, 16, 8), tb, 0, stream>>>(
        Wv, Wo, vT, oT, 512, 512, 262144, 262144, 4);
    transpose_pair_kernel<<<dim3(64, 16, 8), tb, 0, stream>>>(
        fc1c_W, fc1v_W, fc1cT, fc1vT, 512, 2048, 1048576, 1048576, 4);
    transpose_pair_kernel<<<dim3(16, 64, 8), tb, 0, stream>>>(
        fc2c_W, fc2v_W, fc2cT, fc2vT, 2048, 512, 1048576, 1048576, 4);
    transpose_pair_kernel<<<dim3(64, 48, 1), tb, 0, stream>>>(
        hW1, hW1, hW1T, hW1T, 1536, 2048, 0, 0, 1);
    transpose_pair_kernel<<<dim3(8, 64, 1), tb, 0, stream>>>(
        hW2, hW2, hW2T, hW2T, 2048, 256, 0, 0, 1);

    embed_kernel<<<TOK / 4, 256, 0, stream>>>(q, r, ctx_emb, val_emb, pos_emb,
                                              ctx32, val32, ctx16, val16);

    for (int i = 0; i < NBLK; ++i) {
        mfma_gemm<128, true><<<dim3(8, 64), 256, 0, stream>>>(
            (const ushort*)ctx16, (const ushort*)(qkT + (size_t)i * 524288),
            bq + i * DM, bk + i * DM, 512, qk16, 1024, 512, 0, 0,
            nullptr, nullptr, nullptr, nullptr, 1024, 0);
        mfma_gemm<64, true><<<dim3(8, 64), 256, 0, stream>>>(
            (const ushort*)val16, (const ushort*)(vT + (size_t)i * 262144),
            bv + i * DM, nullptr, 1 << 30, vt16, 512, 512, 0, 1,
            nullptr, nullptr, nullptr, nullptr, 512, 0);
        attn_kernel<<<dim3(16, 64), 256, 0, stream>>>(qk16, vt16, att16);
        mfma_gemm<64, true><<<dim3(8, 64), 256, 0, stream>>>(
            (const ushort*)att16, (const ushort*)(oT + (size_t)i * 262144),
            bo + i * DM, nullptr, 1 << 30, ob16c, 512, 512, 0, 0,
            nullptr, nullptr, nullptr, nullptr, 512, 0);
        lnp_kernel<<<dim3(TOK / 4, 2), 256, 0, stream>>>(
            ctx32, ob16c, ln1c_s + i * DM, ln1c_b + i * DM, ctx32, ctx16,
            val32, ob16c, ln1v_s + i * DM, ln1v_b + i * DM, val32, val16);
        mfma_gemm<128, true><<<dim3(16, 64, 2), 256, 0, stream>>>(
            (const ushort*)ctx16, (const ushort*)(fc1cT + (size_t)i * 1048576),
            fc1c_b + i * DFFN, nullptr, 1 << 30, mid16c, 2048, 512, 1, 0,
            (const ushort*)val16, (const ushort*)(fc1vT + (size_t)i * 1048576),
            fc1v_b + i * DFFN, mid16v, 2048, 0);
        mfma_gemm<128, true><<<dim3(4, 64, 2), 256, 0, stream>>>(
            (const ushort*)mid16c, (const ushort*)(fc2cT + (size_t)i * 1048576),
            fc2c_b + i * DM, nullptr, 1 << 30, ob16c, 512, 2048, 0, 0,
            (const ushort*)mid16v, (const ushort*)(fc2vT + (size_t)i * 1048576),
            fc2v_b + i * DM, ob16v, 512, 0);
        lnp_kernel<<<dim3(TOK / 4, 2), 256, 0, stream>>>(
            ctx32, ob16c, ln2c_s + i * DM, ln2c_b + i * DM, ctx32, ctx16,
            val32, ob16v, ln2v_s + i * DM, ln2v_b + i * DM, val32, val16);
    }

    gather_kernel<<<TOK / 4, 256, 0, stream>>>(ctx16, val16, skill_emb, q, feat16);
    mfma_gemm<128, true><<<dim3(16, 64), 256, 0, stream>>>(
        (const ushort*)feat16, (const ushort*)hW1T, hb1, nullptr, 1 << 30, mid16c, 2048, 1536, 1, 0,
        nullptr, nullptr, nullptr, nullptr, 2048, 0);
    mfma_gemm<64, false><<<dim3(4, 64), 256, 0, stream>>>(
        (const ushort*)mid16c, (const ushort*)hW2T, hb2, nullptr, 1 << 30, h2, 256, 2048, 1, 0,
        nullptr, nullptr, nullptr, nullptr, 256, 0);
    logits_kernel<<<TOK / 4, 256, 0, stream>>>(h2, hW3, hb3, out);
}